// Round 9
// baseline (132.593 us; speedup 1.0000x reference)
//
#include <hip/hip_runtime.h>
#include <hip/hip_bf16.h>
#include <math.h>

#define B   8
#define S   64
#define NL  128
#define NPRO 256
#define NN  384   // NL + NPRO
#define P   64
#define NGRP 8
#define EPSF 1e-6f

// ---------------------------------------------------------------------------
// Kernel 1: mean_len[b,s]
// ---------------------------------------------------------------------------
__global__ __launch_bounds__(64) void meanlen_kernel(
    const float* __restrict__ lig, const float* __restrict__ ligmask,
    const float* __restrict__ pro, const float* __restrict__ promask,
    float* __restrict__ meanlen)
{
    int blk = blockIdx.x;              // b*S + s
    int t = threadIdx.x;
    float suml = 0.f, cnt = 0.f;

    const float* lbase = lig + (size_t)blk * NL * 3;
    const float* lm    = ligmask + (size_t)blk * NL;
    for (int n = t; n < NL; n += 64) {
        float x = lbase[n*3+0], y = lbase[n*3+1], z = lbase[n*3+2];
        float mk = lm[n];
        suml += sqrtf(x*x + y*y + z*z) * mk;
        cnt  += mk;
    }
    const float* pbase = pro + (size_t)blk * NPRO * 3;
    const float* pm    = promask + (size_t)blk * NPRO;
    for (int n = t; n < NPRO; n += 64) {
        float x = pbase[n*3+0], y = pbase[n*3+1], z = pbase[n*3+2];
        float mk = pm[n];
        suml += sqrtf(x*x + y*y + z*z) * mk;
        cnt  += mk;
    }
    for (int off = 32; off > 0; off >>= 1) {
        suml += __shfl_down(suml, off);
        cnt  += __shfl_down(cnt,  off);
    }
    if (t == 0) meanlen[blk] = suml / cnt;
}

// ---------------------------------------------------------------------------
// Kernel 2: SoA projection planes
// projc[b,n,p] = sum_s coord[b,s,n,c] * sw[s]/(mean+eps)*mask * w[p,s]
// ---------------------------------------------------------------------------
__global__ __launch_bounds__(64) void proj_kernel(
    const float* __restrict__ lig, const float* __restrict__ pro,
    const float* __restrict__ ligmask, const float* __restrict__ promask,
    const float* __restrict__ ligw, const float* __restrict__ prow,
    const float* __restrict__ sw, const float* __restrict__ meanlen,
    float* __restrict__ projx, float* __restrict__ projy, float* __restrict__ projz)
{
    int blk = blockIdx.x;
    int b = blk / (NN / NGRP);
    int g = blk - b * (NN / NGRP);
    int nbase = g * NGRP;
    int t = threadIdx.x;
    bool isl = (nbase < NL);

    __shared__ float wl[64][65];           // wl[p][s], padded
    const float* w = isl ? ligw : prow;    // (P,S)
    for (int row = 0; row < 64; ++row) wl[row][t] = w[row * 64 + t];

    __shared__ float cs[NGRP][3][64];      // coords premultiplied by g-factor
    {
        int s = t;
        float gfac = sw[s] / (meanlen[b * S + s] + EPSF);
        for (int nn = 0; nn < NGRP; ++nn) {
            int n = nbase + nn;
            float mk, X, Y, Z;
            if (isl) {
                size_t base = ((size_t)b * S + s) * NL + n;
                mk = ligmask[base];
                X = lig[base*3+0]; Y = lig[base*3+1]; Z = lig[base*3+2];
            } else {
                size_t base = ((size_t)b * S + s) * NPRO + (n - NL);
                mk = promask[base];
                X = pro[base*3+0]; Y = pro[base*3+1]; Z = pro[base*3+2];
            }
            float gg = gfac * mk;
            cs[nn][0][s] = X * gg;
            cs[nn][1][s] = Y * gg;
            cs[nn][2][s] = Z * gg;
        }
    }
    __syncthreads();

    for (int nn = 0; nn < NGRP; ++nn) {
        float a0 = 0.f, a1 = 0.f, a2 = 0.f;
        #pragma unroll 8
        for (int s = 0; s < 64; ++s) {
            float wv = wl[t][s];
            a0 += cs[nn][0][s] * wv;
            a1 += cs[nn][1][s] * wv;
            a2 += cs[nn][2][s] * wv;
        }
        size_t base = ((size_t)b * NN + nbase + nn) * P;
        projx[base + t] = a0;
        projy[base + t] = a1;
        projz[base + t] = a2;
    }
}

// ---------------------------------------------------------------------------
// Kernel 3 (dominant, pass 1): block = (b, n-slice of 24, i-chunk of 8).
// Proj points for the slice live in LDS as float4 (one ds_read_b128 per
// element, conflict-free); staged once per block. After the single stage
// barrier, waves are fully independent: wave w handles i = i0 + {2w, 2w+1};
// per i: 24 batched msg loads, 24-elem geometry+softmax (intra-thread
// reduce, lane = p), 5 coalesced stores to partial[row, nsl, acc, p].
// Low VGPR by construction (~50); launch_bounds(256,6) -> 24 waves/CU.
// grid = 8b x 16nsl x 16ic = 2048 blocks x 256 thr.
// `passes` repeats the work loop (passes=1 real; passes=4 diagnostic for
// rocprof visibility above the harness fill dispatches).
// ---------------------------------------------------------------------------
__global__ __launch_bounds__(256, 6) void partial_kernel(
    const float* __restrict__ messages,   // (B, NL, NN, P)
    const int*   __restrict__ adj,        // (B, NL, NN)
    const float* __restrict__ projx,      // (B, NN, P)
    const float* __restrict__ projy,
    const float* __restrict__ projz,
    float* __restrict__ partial,          // (B*NL, 16, 5, 64)
    int passes)
{
    int blk = blockIdx.x;          // b*256 + nsl*16 + ic
    int b   = blk >> 8;
    int nsl = (blk >> 4) & 15;
    int ic  = blk & 15;
    int t = threadIdx.x;
    int wave = t >> 6;             // 0..3
    int p = t & 63;
    int n0 = nsl * 24;
    int i0 = ic * 8;

    __shared__ __align__(16) float4 pl[24][64];   // proj (x,y,z,-) : 24.6 KB
    __shared__ float amk[8][24];                  // additive mask per (il, k)

    for (int idx = t; idx < 24 * 64; idx += 256) {
        int k = idx >> 6, pp = idx & 63;
        size_t g = ((size_t)b * NN + n0 + k) * 64 + pp;
        pl[k][pp] = make_float4(projx[g], projy[g], projz[g], 0.f);
    }
    if (t < 192) {
        int il = t / 24, k = t - il * 24;
        amk[il][k] = adj[((size_t)b * NL + i0 + il) * NN + n0 + k] > 0
                     ? 0.f : -INFINITY;
    }
    __syncthreads();   // only barrier; waves independent afterwards

    #pragma unroll 1
    for (int pass = 0; pass < passes; ++pass) {
        asm volatile("" ::: "memory");   // keep diag passes from CSE/DSE folding
        #pragma unroll 1
        for (int r = 0; r < 2; ++r) {
            int il = wave * 2 + r;
            int i = i0 + il;
            size_t row = (size_t)b * NL + i;
            size_t xidx = ((size_t)b * NN + i) * 64 + p;
            float xix = projx[xidx], xiy = projy[xidx], xiz = projz[xidx];

            const float* mb = messages + (row * NN + n0) * 64 + p;
            float m[24];
            #pragma unroll
            for (int k = 0; k < 24; ++k) m[k] = mb[(size_t)k * 64];

            float s1 = 0.f, s2 = 0.f, a0 = 0.f, a1 = 0.f, a2 = 0.f;
            #pragma unroll
            for (int k = 0; k < 24; ++k) {
                float am = amk[il][k];              // LDS broadcast
                float4 xn = pl[k][p];               // ds_read_b128, conflict-free
                float d0 = xix - xn.x, d1 = xiy - xn.y, d2 = xiz - xn.z;
                float sq = fmaf(d0, d0, fmaf(d1, d1, d2 * d2));
                float inv; asm("v_rsq_f32 %0, %1" : "=v"(inv) : "v"(sq));
                inv = fminf(inv, 1e30f);            // sq==0 -> d==0 -> adds 0
                float xe = fmaf(m[k], 1.44269504f, am);
                float e; asm("v_exp_f32 %0, %1" : "=v"(e) : "v"(xe));
                float ei = e * inv;
                s1 += e; s2 = fmaf(e, e, s2);
                a0 = fmaf(ei, d0, a0); a1 = fmaf(ei, d1, a1); a2 = fmaf(ei, d2, a2);
            }

            float* dst = partial + ((row * 16 + nsl) * 5) * 64 + p;
            dst[0]   = s1;
            dst[64]  = s2;
            dst[128] = a0;
            dst[192] = a1;
            dst[256] = a2;
        }
    }
}

// ---------------------------------------------------------------------------
// Kernel 4 (pass 2): combine 16 n-partials, apply sqrt(S2)/S1^2, project to s.
// ---------------------------------------------------------------------------
__global__ __launch_bounds__(192) void combine_kernel(
    const float* __restrict__ partial,    // (B*NL, 16, 5, 64)
    const float* __restrict__ attn_w,     // (S, P)
    float* __restrict__ out)              // (B, S, NL, 3)
{
    int blk = blockIdx.x;        // b*NL + i
    int b = blk >> 7;
    int i = blk & (NL - 1);
    int t = threadIdx.x;

    __shared__ float upd[3][64];

    if (t < 64) {
        float s1 = 0.f, s2 = 0.f, a0 = 0.f, a1 = 0.f, a2 = 0.f;
        #pragma unroll
        for (int nh = 0; nh < 16; ++nh) {
            size_t base = (((size_t)blk * 16 + nh) * 5) * 64 + t;
            s1 += partial[base];
            s2 += partial[base + 64];
            a0 += partial[base + 128];
            a1 += partial[base + 192];
            a2 += partial[base + 256];
        }
        float wgt = sqrtf(s2) / (s1 * s1);   // (A/S1)*sqrt(S2)/S1
        upd[0][t] = a0 * wgt;
        upd[1][t] = a1 * wgt;
        upd[2][t] = a2 * wgt;
    }
    __syncthreads();

    int s = t & 63, c = t >> 6;
    const float4* aw4 = (const float4*)attn_w + (size_t)s * 16;
    float o = 0.f;
    #pragma unroll
    for (int q = 0; q < 16; ++q) {
        float4 w4 = aw4[q];
        o = fmaf(upd[c][q*4+0], w4.x, o);
        o = fmaf(upd[c][q*4+1], w4.y, o);
        o = fmaf(upd[c][q*4+2], w4.z, o);
        o = fmaf(upd[c][q*4+3], w4.w, o);
    }
    out[(((size_t)b * S + s) * NL + i) * 3 + c] = o;
}

extern "C" void kernel_launch(void* const* d_in, const int* in_sizes, int n_in,
                              void* d_out, int out_size, void* d_ws, size_t ws_size,
                              hipStream_t stream)
{
    const float* lig      = (const float*)d_in[0];   // (B,S,NL,3)
    const float* messages = (const float*)d_in[1];   // (B,NL,NN,P)
    const int*   adj      = (const int*)  d_in[2];   // (B,NL,NN)
    const float* ligmask  = (const float*)d_in[3];   // (B,S,NL)
    const float* pro      = (const float*)d_in[4];   // (B,S,NPRO,3)
    const float* promask  = (const float*)d_in[5];   // (B,S,NPRO)
    const float* ligw     = (const float*)d_in[6];   // (P,S)
    const float* prow     = (const float*)d_in[7];   // (P,S)
    const float* attnw    = (const float*)d_in[8];   // (S,P)
    const float* sw       = (const float*)d_in[9];   // (S,)
    float* out = (float*)d_out;

    const size_t plane = (size_t)B * NN * P;         // 196608 floats
    float* meanlen = (float*)d_ws;                               // 2 KB
    float* projx   = (float*)((char*)d_ws + 2048);
    float* projy   = projx + plane;
    float* projz   = projy + plane;
    float* partial = (float*)((char*)d_ws + (4u << 20));         // 21 MB @ 4MB

    meanlen_kernel<<<B * S, 64, 0, stream>>>(lig, ligmask, pro, promask, meanlen);
    proj_kernel<<<B * (NN / NGRP), 64, 0, stream>>>(lig, pro, ligmask, promask,
                                                    ligw, prow, sw, meanlen,
                                                    projx, projy, projz);
    partial_kernel<<<B * 16 * 16, 256, 0, stream>>>(messages, adj,
                                                    projx, projy, projz,
                                                    partial, 1);
    combine_kernel<<<B * NL, 192, 0, stream>>>(partial, attnw, out);

    // --- diagnostic: same kernel, 4 internal passes, high scratch ->
    // ranks above the ~57us harness fills in rocprof top-k, divide dur by 4.
    if (ws_size >= (64u << 20)) {
        float* diag = (float*)((char*)d_ws + (32u << 20));
        partial_kernel<<<B * 16 * 16, 256, 0, stream>>>(messages, adj,
                                                        projx, projy, projz,
                                                        diag, 4);
    }
}